// Round 8
// baseline (578.532 us; speedup 1.0000x reference)
//
#include <hip/hip_runtime.h>

typedef __bf16 bf16;
typedef __bf16 bf16x8 __attribute__((ext_vector_type(8)));
typedef float  f32x4  __attribute__((ext_vector_type(4)));
typedef float  f32x16 __attribute__((ext_vector_type(16)));

#define AS1 __attribute__((address_space(1)))
#define AS3 __attribute__((address_space(3)))

__device__ __forceinline__ void async16(const void* g, void* l) {
  __builtin_amdgcn_global_load_lds((const AS1 unsigned int*)g, (AS3 unsigned int*)l, 16, 0, 0);
}

// fast tanh-gelu: gelu(u) = u*t/(t+1), t = exp(2*0.79788456*(u+0.044715u^3))
__device__ __forceinline__ float gelu_fast(float u) {
  float z = 0.7978845608028654f * (u + 0.044715f * u * u * u);
  z = fminf(fmaxf(z, -15.f), 15.f);
  float t = __expf(2.f * z);
  return u * t / (t + 1.f);
}

// ---------------- weight transpose + fp32->bf16 : src [z][K][M] -> dst [z][M][K] ----------
template <int FOLD>
__global__ __launch_bounds__(256) void transpose_cvt(
    const float* pbase, const float* gbase, bf16* dst, int K, int M,
    const float* lnsP, const float* lnbP, const float* lnsG, const float* lnbG,
    const float* b0P, const float* b0G, float* bias_eff) {
  __shared__ float tile[32][33];
  const int z = blockIdx.z;
  const float* src = (z < 4) ? pbase + (size_t)z * K * M : gbase;
  bf16* d = dst + (size_t)z * M * K;
  const int mBlk = blockIdx.x * 32, kBlk = blockIdx.y * 32;
  const int tx = threadIdx.x, ty = threadIdx.y;
  for (int i = 0; i < 4; i++)
    tile[ty + i * 8][tx] = src[(size_t)(kBlk + ty + i * 8) * M + mBlk + tx];
  __syncthreads();
  if constexpr (FOLD) {
    const float* s  = (z < 4) ? lnsP + (size_t)z * 512 : lnsG;
    const float* bb = (z < 4) ? lnbP + (size_t)z * 512 : lnbG;
    const float sk = s[kBlk + tx];
    for (int i = 0; i < 4; i++)
      d[(size_t)(mBlk + ty + i * 8) * K + kBlk + tx] = (bf16)(tile[tx][ty + i * 8] * sk);
    if (ty == 0) {
      float acc = 0.f;
      for (int kk = 0; kk < 32; kk++) acc += bb[kBlk + kk] * tile[kk][tx];
      if (kBlk == 0) {
        const float* b0 = (z < 4) ? b0P + (size_t)z * M : b0G;
        acc += b0[mBlk + tx];
      }
      atomicAdd(&bias_eff[(size_t)z * M + mBlk + tx], acc);
    }
  } else {
    for (int i = 0; i < 4; i++)
      d[(size_t)(mBlk + ty + i * 8) * K + kBlk + tx] = (bf16)tile[tx][ty + i * 8];
  }
}

// ---------------- LN1 (shared): xn = (x - m) * rsqrt(var) ---------------------------------
__global__ __launch_bounds__(256) void ln_plain(const float* x, bf16* out) {
  const int t = blockIdx.x, tid = threadIdx.x;
  const float* xr = x + (size_t)t * 512;
  float v0 = xr[tid], v1 = xr[tid + 256];
  float s1 = v0 + v1, s2 = v0 * v0 + v1 * v1;
  for (int off = 32; off > 0; off >>= 1) { s1 += __shfl_down(s1, off); s2 += __shfl_down(s2, off); }
  __shared__ float red[8];
  __shared__ float mv[2];
  if ((tid & 63) == 0) { red[tid >> 6] = s1; red[4 + (tid >> 6)] = s2; }
  __syncthreads();
  if (tid == 0) {
    float a = red[0] + red[1] + red[2] + red[3];
    float b = red[4] + red[5] + red[6] + red[7];
    float mean = a * (1.f / 512.f);
    float var = b * (1.f / 512.f) - mean * mean;
    mv[0] = mean; mv[1] = 1.f / sqrtf(var + 1e-5f);
  }
  __syncthreads();
  const float mean = mv[0], rs = mv[1];
  bf16* o = out + (size_t)t * 512;
  o[tid]       = (bf16)((v0 - mean) * rs);
  o[tid + 256] = (bf16)((v1 - mean) * rs);
}

// ---------------- LN2 (per-expert, bf16 in, applies scale/bias) ---------------------------
__global__ __launch_bounds__(256) void ln2_kernel(const bf16* in, const float* sP, const float* bP,
                                                  const float* sG, const float* bG, bf16* out) {
  const int t = blockIdx.x, z = blockIdx.y, tid = threadIdx.x;
  const bf16* xr = in + (size_t)z * 4096 * 512 + (size_t)t * 512;
  float v0 = (float)xr[tid], v1 = (float)xr[tid + 256];
  float s1 = v0 + v1, s2 = v0 * v0 + v1 * v1;
  for (int off = 32; off > 0; off >>= 1) { s1 += __shfl_down(s1, off); s2 += __shfl_down(s2, off); }
  __shared__ float red[8];
  __shared__ float mv[2];
  if ((tid & 63) == 0) { red[tid >> 6] = s1; red[4 + (tid >> 6)] = s2; }
  __syncthreads();
  if (tid == 0) {
    float a = red[0] + red[1] + red[2] + red[3];
    float b = red[4] + red[5] + red[6] + red[7];
    float mean = a * (1.f / 512.f);
    float var = b * (1.f / 512.f) - mean * mean;
    mv[0] = mean; mv[1] = 1.f / sqrtf(var + 1e-5f);
  }
  __syncthreads();
  const float mean = mv[0], rs = mv[1];
  const float* sc = (z < 4) ? sP + (size_t)z * 512 : sG;
  const float* bi = (z < 4) ? bP + (size_t)z * 512 : bG;
  bf16* o = out + (size_t)z * 4096 * 512 + (size_t)t * 512;
  o[tid]       = (bf16)((v0 - mean) * rs * sc[tid] + bi[tid]);
  o[tid + 256] = (bf16)((v1 - mean) * rs * sc[tid + 256] + bi[tid + 256]);
}

// ---------------- MFMA GEMM: 4x2 wave tile (wave=128m x 64n, block=256x128) ---------------
// LDS: As[256x64]=32KB @0, Bs[128x64]=16KB @16384el. 6 b128 reads feed 8 MFMA per ks.
// MODE 0: out=gemm+bias (QKV)  1: +resid fp32 (WO)  2: gelu (FFN1)  3: +resid bf16 (FFN2)
template <int MODE>
__global__ __launch_bounds__(256, 2) void gemm_bt(
    const bf16* Abase, long long aStrideZ, const bf16* Wt,
    const float* biasP, const float* biasG, int K, int M,
    bf16* out, const void* resid, long long residStrideZ) {
  const int z = blockIdx.z;
  // L2 group swizzle: consecutive ids cover 4 by x all bx
  const int id = blockIdx.x + gridDim.x * blockIdx.y;
  const int W = gridDim.x, band = id / (W * 4), within = id % (W * 4);
  const int by = band * 4 + (within & 3), bx = within >> 2;
  const bf16* A = Abase + (size_t)z * aStrideZ;
  const bf16* B = Wt + (size_t)z * M * K;
  const float* bias = (z < 4) ? biasP + (size_t)z * M : biasG;
  __shared__ bf16 smem[24576];                     // As[0,16384) Bs[16384,24576); epi reuse
  bf16* As = smem;
  bf16* Bs = smem + 16384;
  const int tid = threadIdx.x, wave = tid >> 6, l = tid & 63;
  const int l31 = l & 31, lh = l >> 5;
  const int wm = wave & 1, wn = wave >> 1;       // wm: m-half (128 rows), wn: n-half (64 cols)
  f32x16 acc[4][2];
  for (int i = 0; i < 4; i++) for (int j = 0; j < 2; j++)
    for (int r = 0; r < 16; r++) acc[i][j][r] = 0.f;
  const int rowA0 = by * 256, rowB0 = bx * 128;

  for (int kt = 0; kt < K; kt += 64) {
    __syncthreads();
    for (int i = 0; i < 8; i++) {                 // A: 256 rows
      int s = i * 256 + tid, r = s >> 3, kb = s & 7;
      int col = kt + ((kb ^ ((r ^ (r >> 3)) & 7)) << 3);
      async16(A + (size_t)(rowA0 + r) * K + col, &As[(i * 256 + wave * 64) * 8]);
    }
    for (int i = 0; i < 4; i++) {                 // B: 128 rows
      int s = i * 256 + tid, r = s >> 3, kb = s & 7;
      int col = kt + ((kb ^ ((r ^ (r >> 3)) & 7)) << 3);
      async16(B + (size_t)(rowB0 + r) * K + col, &Bs[(i * 256 + wave * 64) * 8]);
    }
    __syncthreads();
    for (int ks = 0; ks < 4; ks++) {
      bf16x8 af[4], bfr[2];
      for (int ti = 0; ti < 4; ti++) {
        int r = wm * 128 + ti * 32 + l31;
        int kb = (ks * 2 + lh) ^ ((r ^ (r >> 3)) & 7);
        af[ti] = *(const bf16x8*)&As[r * 64 + (kb << 3)];
      }
      for (int ni = 0; ni < 2; ni++) {
        int r = wn * 64 + ni * 32 + l31;
        int kb = (ks * 2 + lh) ^ ((r ^ (r >> 3)) & 7);
        bfr[ni] = *(const bf16x8*)&Bs[r * 64 + (kb << 3)];
      }
      for (int ti = 0; ti < 4; ti++)
        for (int ni = 0; ni < 2; ni++)
          acc[ti][ni] = __builtin_amdgcn_mfma_f32_32x32x16_bf16(af[ti], bfr[ni], acc[ti][ni], 0, 0, 0);
    }
  }

  // ---- epilogue: two 128-row passes through LDS (C layout: col=l31, row=(reg&3)+8*(reg>>2)+4*lh)
  __syncthreads();
  bf16* ob = out + (size_t)z * 4096 * M;
  for (int p2 = 0; p2 < 2; p2++) {
    if (wm == p2) {
      for (int ti = 0; ti < 4; ti++)
        for (int ni = 0; ni < 2; ni++) {
          int coll = wn * 64 + ni * 32 + l31;
          float bb = bias[rowB0 + coll];
          for (int reg = 0; reg < 16; reg++) {
            int row = ti * 32 + (reg & 3) + 8 * (reg >> 2) + 4 * lh;
            float v = acc[ti][ni][reg] + bb;
            if constexpr (MODE == 2) v = gelu_fast(v);
            smem[row * 136 + coll] = (bf16)v;
          }
        }
    }
    __syncthreads();
    for (int p = 0; p < 8; p++) {
      int r = p * 16 + (tid >> 4), c0 = (tid & 15) * 8;
      int grow = rowA0 + p2 * 128 + r;
      bf16x8 vv = *(const bf16x8*)&smem[r * 136 + c0];
      if constexpr (MODE == 1) {
        const float* rx = (const float*)resid + (size_t)grow * 512 + rowB0 + c0;
        for (int j = 0; j < 8; j++) vv[j] = (bf16)((float)vv[j] + rx[j]);
      } else if constexpr (MODE == 3) {
        const bf16* rx = (const bf16*)resid + (size_t)z * residStrideZ + (size_t)grow * 512 + rowB0 + c0;
        bf16x8 rv = *(const bf16x8*)rx;
        for (int j = 0; j < 8; j++) vv[j] = (bf16)((float)vv[j] + (float)rv[j]);
      }
      *(bf16x8*)&ob[(size_t)grow * M + rowB0 + c0] = vv;
    }
    if (p2 == 0) __syncthreads();
  }
}

// ---------------- fused attention: dbuf K/V pipeline, fixed-max softmax -------------------
__global__ __launch_bounds__(256, 2) void attn_kernel(const bf16* qkv, bf16* o) {
  const int qt = blockIdx.x >> 6, bh = blockIdx.x & 63, z = blockIdx.y;  // same-head blocks share XCD
  const int b = bh >> 3, h = bh & 7;
  const bf16* base = qkv + (size_t)z * 4096 * 1536 + (size_t)b * 512 * 1536;
  __shared__ bf16 smem[30208];
  bf16* Vt = smem + 16384;
  bf16* Q_area = smem + 16384;
  const int tid = threadIdx.x, wave = tid >> 6, l = tid & 63;
  const int m16 = l & 15, q4 = l >> 4;
  bf16* pw = smem + 20992 + wave * 32 * 72;
  f32x4 zero4 = {0.f, 0.f, 0.f, 0.f};

  for (int i = 0; i < 4; i++) {
    int s = i * 256 + tid, r = s >> 3, kb = s & 7;
    async16(base + (size_t)(qt * 128 + r) * 1536 + h * 64 + ((kb ^ (r & 7)) << 3),
            &Q_area[(i * 256 + wave * 64) * 8]);
  }
  for (int i = 0; i < 2; i++) {
    int s = i * 256 + tid, r = s >> 3, kb = s & 7;
    async16(base + (size_t)r * 1536 + 512 + h * 64 + ((kb ^ (r & 7)) << 3),
            &smem[(i * 256 + wave * 64) * 8]);               // Ks buf0 = [0,4096)
    async16(base + (size_t)r * 1536 + 1024 + h * 64 + (kb << 3),
            &smem[8192 + (i * 256 + wave * 64) * 8]);        // Vs buf0 = [8192,12288)
  }
  f32x4 Oacc[2][4];
  float l_run[2][4];
  for (int rt = 0; rt < 2; rt++)
    for (int cr = 0; cr < 4; cr++) l_run[rt][cr] = 0.f;
  for (int rt = 0; rt < 2; rt++) for (int dt = 0; dt < 4; dt++) Oacc[rt][dt] = zero4;
  __syncthreads();
  bf16x8 qf[2][2];
  for (int rt = 0; rt < 2; rt++)
    for (int ks = 0; ks < 2; ks++) {
      int r = wave * 32 + rt * 16 + m16, kb = ks * 4 + q4;
      bf16x8 q8 = *(const bf16x8*)&Q_area[r * 64 + ((kb ^ (r & 7)) << 3)];
      for (int j = 0; j < 8; j++) q8[j] = (bf16)((float)q8[j] * 0.125f);
      qf[rt][ks] = q8;
    }
  __syncthreads();

  for (int kt = 0; kt < 8; kt++) {
    const int cur = kt & 1, nxt = cur ^ 1;
    bf16* Ks = smem + cur * 4096;
    bf16* Vs = smem + 8192 + cur * 4096;
    bf16* Ksn = smem + nxt * 4096;
    bf16* Vsn = smem + 8192 + nxt * 4096;
    if (kt > 0) __syncthreads();
    if (kt < 7) {
      for (int i = 0; i < 2; i++) {
        int s = i * 256 + tid, r = s >> 3, kb = s & 7;
        async16(base + (size_t)((kt + 1) * 64 + r) * 1536 + 512 + h * 64 + ((kb ^ (r & 7)) << 3),
                &Ksn[(i * 256 + wave * 64) * 8]);
        async16(base + (size_t)((kt + 1) * 64 + r) * 1536 + 1024 + h * 64 + (kb << 3),
                &Vsn[(i * 256 + wave * 64) * 8]);
      }
    }
    {
      int d = tid & 63, kb2 = (tid >> 6) * 16;
      for (int g = 0; g < 2; g++) {
        int kbase = kb2 + g * 8;
        bf16 tmp[8];
        for (int j = 0; j < 8; j++) tmp[j] = Vs[(kbase + j) * 64 + d];
        *(bf16x8*)&Vt[d * 72 + kbase] = *(const bf16x8*)tmp;
      }
    }
    f32x4 S[2][4];
    for (int rt = 0; rt < 2; rt++)
      for (int ct = 0; ct < 4; ct++) {
        f32x4 a = zero4;
        for (int ks = 0; ks < 2; ks++) {
          int n = ct * 16 + m16, kb = (ks * 4 + q4) ^ (n & 7);
          bf16x8 kf = *(const bf16x8*)&Ks[n * 64 + (kb << 3)];
          a = __builtin_amdgcn_mfma_f32_16x16x32_bf16(qf[rt][ks], kf, a, 0, 0, 0);
        }
        S[rt][ct] = a;
      }
    for (int rt = 0; rt < 2; rt++)
      for (int cr = 0; cr < 4; cr++) {
        float rs = 0.f;
        for (int ct = 0; ct < 4; ct++) {
          float p = __expf(S[rt][ct][cr]);
          S[rt][ct][cr] = p; rs += p;
        }
        rs += __shfl_xor(rs, 1); rs += __shfl_xor(rs, 2);
        rs += __shfl_xor(rs, 4); rs += __shfl_xor(rs, 8);
        l_run[rt][cr] += rs;
      }
    for (int rt = 0; rt < 2; rt++)
      for (int ct = 0; ct < 4; ct++)
        for (int cr = 0; cr < 4; cr++)
          pw[(rt * 16 + q4 * 4 + cr) * 72 + ct * 16 + m16] = (bf16)S[rt][ct][cr];
    __syncthreads();
    for (int rt = 0; rt < 2; rt++)
      for (int dt = 0; dt < 4; dt++) {
        f32x4 a = Oacc[rt][dt];
        for (int ks = 0; ks < 2; ks++) {
          bf16x8 pf = *(const bf16x8*)&pw[(rt * 16 + m16) * 72 + ks * 32 + q4 * 8];
          bf16x8 vf = *(const bf16x8*)&Vt[(dt * 16 + m16) * 72 + ks * 32 + q4 * 8];
          a = __builtin_amdgcn_mfma_f32_16x16x32_bf16(pf, vf, a, 0, 0, 0);
        }
        Oacc[rt][dt] = a;
      }
  }
  bf16* ob = o + (size_t)z * 4096 * 512 + (size_t)(b * 512 + qt * 128 + wave * 32) * 512 + h * 64;
  for (int rt = 0; rt < 2; rt++)
    for (int dt = 0; dt < 4; dt++)
      for (int cr = 0; cr < 4; cr++) {
        int r = rt * 16 + q4 * 4 + cr;
        ob[(size_t)r * 512 + dt * 16 + m16] = (bf16)(Oacc[rt][dt][cr] / l_run[rt][cr]);
      }
}

// ---------------- stats: prim_sum fp32, per-expert col sums, uvar partials ----------------
__global__ __launch_bounds__(256) void stats_k(const bf16* eout, const float* x,
                                               float* prim_sum, float* mean_acc, float* accum) {
  const int r0 = blockIdx.x * 32;
  const int tid = threadIdx.x;
  const int c0 = tid * 2;
  float cs[4][2] = {{0.f,0.f},{0.f,0.f},{0.f,0.f},{0.f,0.f}};
  float sd = 0.f, sd2 = 0.f;
  for (int rr = 0; rr < 32; rr++) {
    int row = r0 + rr;
    float s0 = 0.f, s1 = 0.f;
    for (int e = 0; e < 4; e++) {
      const bf16* p = &eout[((size_t)e * 4096 + row) * 512 + c0];
      float f0 = (float)p[0], f1 = (float)p[1];
      cs[e][0] += f0; cs[e][1] += f1;
      s0 += f0; s1 += f1;
    }
    prim_sum[(size_t)row * 512 + c0]     = s0;
    prim_sum[(size_t)row * 512 + c0 + 1] = s1;
    float d0 = x[(size_t)row * 512 + c0]     - s0 * 0.25f;
    float d1 = x[(size_t)row * 512 + c0 + 1] - s1 * 0.25f;
    sd += d0 + d1; sd2 += d0 * d0 + d1 * d1;
  }
  for (int e = 0; e < 4; e++) {
    atomicAdd(&mean_acc[e * 512 + c0],     cs[e][0]);
    atomicAdd(&mean_acc[e * 512 + c0 + 1], cs[e][1]);
  }
  for (int off = 32; off > 0; off >>= 1) { sd += __shfl_down(sd, off); sd2 += __shfl_down(sd2, off); }
  __shared__ float r1[4], r2[4];
  if ((tid & 63) == 0) { r1[tid >> 6] = sd; r2[tid >> 6] = sd2; }
  __syncthreads();
  if (tid == 0) {
    atomicAdd(&accum[0], r1[0] + r1[1] + r1[2] + r1[3]);
    atomicAdd(&accum[1], r2[0] + r2[1] + r2[2] + r2[3]);
  }
}

// ---------------- finalize: ortho * uvar -> rate ------------------------------------------
__global__ void finalize_k(const float* mean_acc, const float* accum, float* rate) {
  const int l = threadIdx.x;
  float me[4][8];
  for (int e = 0; e < 4; e++)
    for (int j = 0; j < 8; j++) me[e][j] = mean_acc[e * 512 + l * 8 + j] * (1.f / 4096.f);
  float dot[4][4];
  for (int e = 0; e < 4; e++)
    for (int f = e; f < 4; f++) {
      float d = 0.f;
      for (int j = 0; j < 8; j++) d += me[e][j] * me[f][j];
      for (int off = 32; off > 0; off >>= 1) d += __shfl_xor(d, off);
      dot[e][f] = d; dot[f][e] = d;
    }
  float nrm[4];
  for (int e = 0; e < 4; e++) nrm[e] = sqrtf(dot[e][e]);
  float acc = 0.f;
  for (int e = 0; e < 4; e++)
    for (int f = 0; f < 4; f++) {
      float g = dot[e][f] / (nrm[e] * nrm[f]) - (e == f ? 1.f : 0.f);
      acc += g * g;
    }
  float ortho = 1.f - acc * (1.f / 16.f);
  float n = 2097152.f;
  float uvar = (accum[1] - accum[0] * accum[0] / n) / (n - 1.f);
  float sat = ortho * uvar;
  if (l == 0) rate[0] = (sat > 0.01f) ? 0.01f : 0.f;
}

// ---------------- combine: out = (prim_sum + rate*ghost)/6 --------------------------------
__global__ __launch_bounds__(256) void combine_k(const float* prim, const bf16* ghost,
                                                 const float* rate, float* out) {
  float r = rate[0];
  int i = blockIdx.x * 256 + threadIdx.x;
  f32x4 p = ((const f32x4*)prim)[i];
  const bf16* g = ghost + (size_t)i * 4;
  f32x4 o;
  for (int j = 0; j < 4; j++) o[j] = (p[j] + r * (float)g[j]) * (1.f / 6.f);
  ((f32x4*)out)[i] = o;
}

extern "C" void kernel_launch(void* const* d_in, const int* in_sizes, int n_in,
                              void* d_out, int out_size, void* d_ws, size_t ws_size,
                              hipStream_t stream) {
  const float* x       = (const float*)d_in[0];
  const float* p_ln1_s = (const float*)d_in[2];
  const float* p_ln1_b = (const float*)d_in[3];
  const float* p_wqkv  = (const float*)d_in[4];
  const float* p_bqkv  = (const float*)d_in[5];
  const float* p_wo    = (const float*)d_in[6];
  const float* p_bo    = (const float*)d_in[7];
  const float* p_ln2_s = (const float*)d_in[8];
  const float* p_ln2_b = (const float*)d_in[9];
  const float* p_w1    = (const float*)d_in[10];
  const float* p_b1    = (const float*)d_in[11];
  const float* p_w2    = (const float*)d_in[12];
  const float* p_b2    = (const float*)d_in[13];
  const float* g_ln1_s = (const float*)d_in[14];
  const float* g_ln1_b = (const float*)d_in[15];
  const float* g_wqkv  = (const float*)d_in[16];
  const float* g_bqkv  = (const float*)d_in[17];
  const float* g_wo    = (const float*)d_in[18];
  const float* g_bo    = (const float*)d_in[19];
  const float* g_ln2_s = (const float*)d_in[20];
  const float* g_ln2_b = (const float*)d_in[21];
  const float* g_w1    = (const float*)d_in[22];
  const float* g_b1    = (const float*)d_in[23];
  const float* g_w2    = (const float*)d_in[24];
  const float* g_b2    = (const float*)d_in[25];

  char* ws = (char*)d_ws;
  size_t off = 0;
  auto alloc = [&](size_t bytes) { void* p = ws + off; off += (bytes + 255) & ~(size_t)255; return p; };
  bf16* wt_qkv   = (bf16*)alloc(5ull * 1536 * 512 * 2);
  bf16* wt_wo    = (bf16*)alloc(5ull * 512 * 512 * 2);
  bf16* wt_w1    = (bf16*)alloc(5ull * 2048 * 512 * 2);
  bf16* wt_w2    = (bf16*)alloc(5ull * 512 * 2048 * 2);
  bf16* xn       = (bf16*)alloc(4096ull * 512 * 2);       // shared LN1 output
  bf16* act_a    = (bf16*)alloc(5ull * 4096 * 512 * 2);   // attn-out -> h
  bf16* big      = (bf16*)alloc(5ull * 4096 * 2048 * 2);  // qkv (1536 cols) -> ff (2048)
  bf16* x1       = (bf16*)alloc(5ull * 4096 * 512 * 2);
  bf16* eout     = (bf16*)alloc(5ull * 4096 * 512 * 2);   // per-expert block outputs
  float* prim_sum = (float*)alloc(4096ull * 512 * 4);
  float* bias_eff = (float*)alloc(5ull * 1536 * 4);
  float* mean_acc = (float*)alloc(4 * 512 * 4);
  float* accum    = (float*)alloc(256);

  (void)hipMemsetAsync(bias_eff, 0, 5ull * 1536 * 4, stream);
  (void)hipMemsetAsync(mean_acc, 0, 4 * 512 * 4, stream);
  (void)hipMemsetAsync(accum, 0, 16, stream);

  dim3 tb(32, 8);
  transpose_cvt<1><<<dim3(48, 16, 5), tb, 0, stream>>>(p_wqkv, g_wqkv, wt_qkv, 512, 1536,
      p_ln1_s, p_ln1_b, g_ln1_s, g_ln1_b, p_bqkv, g_bqkv, bias_eff);
  transpose_cvt<0><<<dim3(16, 16, 5), tb, 0, stream>>>(p_wo, g_wo, wt_wo, 512, 512,
      nullptr, nullptr, nullptr, nullptr, nullptr, nullptr, nullptr);
  transpose_cvt<0><<<dim3(64, 16, 5), tb, 0, stream>>>(p_w1, g_w1, wt_w1, 512, 2048,
      nullptr, nullptr, nullptr, nullptr, nullptr, nullptr, nullptr);
  transpose_cvt<0><<<dim3(16, 64, 5), tb, 0, stream>>>(p_w2, g_w2, wt_w2, 2048, 512,
      nullptr, nullptr, nullptr, nullptr, nullptr, nullptr, nullptr);

  ln_plain<<<dim3(4096), 256, 0, stream>>>(x, xn);
  gemm_bt<0><<<dim3(12, 16, 5), 256, 0, stream>>>(xn, 0, wt_qkv, bias_eff, bias_eff + 4ull * 1536,
                                                  512, 1536, big, nullptr, 0);
  attn_kernel<<<dim3(256, 5), 256, 0, stream>>>(big, act_a);
  gemm_bt<1><<<dim3(4, 16, 5), 256, 0, stream>>>(act_a, 4096ll * 512, wt_wo, p_bo, g_bo,
                                                 512, 512, x1, x, 0);
  ln2_kernel<<<dim3(4096, 5), 256, 0, stream>>>(x1, p_ln2_s, p_ln2_b, g_ln2_s, g_ln2_b, act_a);
  gemm_bt<2><<<dim3(16, 16, 5), 256, 0, stream>>>(act_a, 4096ll * 512, wt_w1, p_b1, g_b1,
                                                  512, 2048, big, nullptr, 0);
  gemm_bt<3><<<dim3(4, 16, 5), 256, 0, stream>>>(big, 4096ll * 2048, wt_w2, p_b2, g_b2,
                                                 2048, 512, eout, x1, 4096ll * 512);
  stats_k<<<dim3(128), 256, 0, stream>>>(eout, x, prim_sum, mean_acc, accum);
  finalize_k<<<1, 64, 0, stream>>>(mean_acc, accum, accum + 2);
  combine_k<<<dim3(2048), 256, 0, stream>>>(prim_sum, eout + 4ull * 4096 * 512, accum + 2, (float*)d_out);
}

// Round 9
// 470.914 us; speedup vs baseline: 1.2285x; 1.2285x over previous
//
#include <hip/hip_runtime.h>

typedef __bf16 bf16;
typedef __bf16 bf16x8 __attribute__((ext_vector_type(8)));
typedef float  f32x4  __attribute__((ext_vector_type(4)));
typedef float  f32x16 __attribute__((ext_vector_type(16)));

#define AS1 __attribute__((address_space(1)))
#define AS3 __attribute__((address_space(3)))

__device__ __forceinline__ void async16(const void* g, void* l) {
  __builtin_amdgcn_global_load_lds((const AS1 unsigned int*)g, (AS3 unsigned int*)l, 16, 0, 0);
}

// fast tanh-gelu: gelu(u) = u*t/(t+1), t = exp(2*0.79788456*(u+0.044715u^3))
__device__ __forceinline__ float gelu_fast(float u) {
  float z = 0.7978845608028654f * (u + 0.044715f * u * u * u);
  z = fminf(fmaxf(z, -15.f), 15.f);
  float t = __expf(2.f * z);
  return u * t / (t + 1.f);
}

// ---------------- weight transpose + fp32->bf16 : src [z][K][M] -> dst [z][M][K] ----------
template <int FOLD>
__global__ __launch_bounds__(256) void transpose_cvt(
    const float* pbase, const float* gbase, bf16* dst, int K, int M,
    const float* lnsP, const float* lnbP, const float* lnsG, const float* lnbG,
    const float* b0P, const float* b0G, float* bias_eff) {
  __shared__ float tile[32][33];
  const int z = blockIdx.z;
  const float* src = (z < 4) ? pbase + (size_t)z * K * M : gbase;
  bf16* d = dst + (size_t)z * M * K;
  const int mBlk = blockIdx.x * 32, kBlk = blockIdx.y * 32;
  const int tx = threadIdx.x, ty = threadIdx.y;
  for (int i = 0; i < 4; i++)
    tile[ty + i * 8][tx] = src[(size_t)(kBlk + ty + i * 8) * M + mBlk + tx];
  __syncthreads();
  if constexpr (FOLD) {
    const float* s  = (z < 4) ? lnsP + (size_t)z * 512 : lnsG;
    const float* bb = (z < 4) ? lnbP + (size_t)z * 512 : lnbG;
    const float sk = s[kBlk + tx];
    for (int i = 0; i < 4; i++)
      d[(size_t)(mBlk + ty + i * 8) * K + kBlk + tx] = (bf16)(tile[tx][ty + i * 8] * sk);
    if (ty == 0) {
      float acc = 0.f;
      for (int kk = 0; kk < 32; kk++) acc += bb[kBlk + kk] * tile[kk][tx];
      if (kBlk == 0) {
        const float* b0 = (z < 4) ? b0P + (size_t)z * M : b0G;
        acc += b0[mBlk + tx];
      }
      atomicAdd(&bias_eff[(size_t)z * M + mBlk + tx], acc);
    }
  } else {
    for (int i = 0; i < 4; i++)
      d[(size_t)(mBlk + ty + i * 8) * K + kBlk + tx] = (bf16)tile[tx][ty + i * 8];
  }
}

// ---------------- LN1 (shared): xn = (x - m) * rsqrt(var) ---------------------------------
__global__ __launch_bounds__(256) void ln_plain(const float* x, bf16* out) {
  const int t = blockIdx.x, tid = threadIdx.x;
  const float* xr = x + (size_t)t * 512;
  float v0 = xr[tid], v1 = xr[tid + 256];
  float s1 = v0 + v1, s2 = v0 * v0 + v1 * v1;
  for (int off = 32; off > 0; off >>= 1) { s1 += __shfl_down(s1, off); s2 += __shfl_down(s2, off); }
  __shared__ float red[8];
  __shared__ float mv[2];
  if ((tid & 63) == 0) { red[tid >> 6] = s1; red[4 + (tid >> 6)] = s2; }
  __syncthreads();
  if (tid == 0) {
    float a = red[0] + red[1] + red[2] + red[3];
    float b = red[4] + red[5] + red[6] + red[7];
    float mean = a * (1.f / 512.f);
    float var = b * (1.f / 512.f) - mean * mean;
    mv[0] = mean; mv[1] = 1.f / sqrtf(var + 1e-5f);
  }
  __syncthreads();
  const float mean = mv[0], rs = mv[1];
  bf16* o = out + (size_t)t * 512;
  o[tid]       = (bf16)((v0 - mean) * rs);
  o[tid + 256] = (bf16)((v1 - mean) * rs);
}

// ---------------- LN2 (per-expert, bf16 in, applies scale/bias) ---------------------------
__global__ __launch_bounds__(256) void ln2_kernel(const bf16* in, const float* sP, const float* bP,
                                                  const float* sG, const float* bG, bf16* out) {
  const int t = blockIdx.x, z = blockIdx.y, tid = threadIdx.x;
  const bf16* xr = in + (size_t)z * 4096 * 512 + (size_t)t * 512;
  float v0 = (float)xr[tid], v1 = (float)xr[tid + 256];
  float s1 = v0 + v1, s2 = v0 * v0 + v1 * v1;
  for (int off = 32; off > 0; off >>= 1) { s1 += __shfl_down(s1, off); s2 += __shfl_down(s2, off); }
  __shared__ float red[8];
  __shared__ float mv[2];
  if ((tid & 63) == 0) { red[tid >> 6] = s1; red[4 + (tid >> 6)] = s2; }
  __syncthreads();
  if (tid == 0) {
    float a = red[0] + red[1] + red[2] + red[3];
    float b = red[4] + red[5] + red[6] + red[7];
    float mean = a * (1.f / 512.f);
    float var = b * (1.f / 512.f) - mean * mean;
    mv[0] = mean; mv[1] = 1.f / sqrtf(var + 1e-5f);
  }
  __syncthreads();
  const float mean = mv[0], rs = mv[1];
  const float* sc = (z < 4) ? sP + (size_t)z * 512 : sG;
  const float* bi = (z < 4) ? bP + (size_t)z * 512 : bG;
  bf16* o = out + (size_t)z * 4096 * 512 + (size_t)t * 512;
  o[tid]       = (bf16)((v0 - mean) * rs * sc[tid] + bi[tid]);
  o[tid + 256] = (bf16)((v1 - mean) * rs * sc[tid + 256] + bi[tid + 256]);
}

// ---------------- MFMA GEMM (32x32x16 core, 128x128 tile, 4 blocks/CU) --------------------
// R6 structure + L2 group swizzle + kt-invariant LDS addresses hoisted out of the K-loop.
// MODE 0: out=gemm+bias (QKV)  1: +resid fp32 (WO)  2: gelu (FFN1)  3: +resid bf16 (FFN2)
template <int MODE>
__global__ __launch_bounds__(256, 4) void gemm_bt(
    const bf16* Abase, long long aStrideZ, const bf16* Wt,
    const float* biasP, const float* biasG, int K, int M,
    bf16* out, const void* resid, long long residStrideZ) {
  const int z = blockIdx.z;
  // L2 group swizzle: consecutive ids cover 4 by x all bx
  const int id = blockIdx.x + gridDim.x * blockIdx.y;
  const int W = gridDim.x, band = id / (W * 4), within = id % (W * 4);
  const int by = band * 4 + (within & 3), bx = within >> 2;
  const bf16* A = Abase + (size_t)z * aStrideZ;
  const bf16* B = Wt + (size_t)z * M * K;
  const float* bias = (z < 4) ? biasP + (size_t)z * M : biasG;
  __shared__ bf16 smem[128 * 136];                 // K-loop: As=[0,8192) Bs=[8192,16384); epi: Cs
  bf16* As = smem;
  bf16* Bs = smem + 128 * 64;
  const int tid = threadIdx.x, wave = tid >> 6, l = tid & 63;
  const int l31 = l & 31, lh = l >> 5;
  const int wm = wave & 1, wn = wave >> 1;
  f32x16 acc[2][2];
  for (int i = 0; i < 2; i++) for (int j = 0; j < 2; j++)
    for (int r = 0; r < 16; r++) acc[i][j][r] = 0.f;
  const int rowA0 = by * 128, rowB0 = bx * 128;

  // hoisted staging source pointers (advance 64 elements per K-tile)
  const int r0 = tid >> 3, kb0 = tid & 7;
  const bf16* ap[4];
  const bf16* bp[4];
  for (int i = 0; i < 4; i++) {
    int r = i * 32 + r0;
    int cs = (kb0 ^ ((r ^ (r >> 3)) & 7)) << 3;
    ap[i] = A + (size_t)(rowA0 + r) * K + cs;
    bp[i] = B + (size_t)(rowB0 + r) * K + cs;
  }
  // hoisted kt-invariant fragment LDS offsets
  int aoff[4][2], boff[4][2];
  for (int ks = 0; ks < 4; ks++) {
    for (int ti = 0; ti < 2; ti++) {
      int r = wm * 64 + ti * 32 + l31;
      aoff[ks][ti] = r * 64 + (((ks * 2 + lh) ^ ((r ^ (r >> 3)) & 7)) << 3);
    }
    for (int ni = 0; ni < 2; ni++) {
      int r = wn * 64 + ni * 32 + l31;
      boff[ks][ni] = r * 64 + (((ks * 2 + lh) ^ ((r ^ (r >> 3)) & 7)) << 3);
    }
  }

  for (int kt = 0; kt < K; kt += 64) {
    __syncthreads();
    for (int i = 0; i < 4; i++) {
      async16(ap[i] + kt, &As[(i * 256 + wave * 64) * 8]);
      async16(bp[i] + kt, &Bs[(i * 256 + wave * 64) * 8]);
    }
    __syncthreads();
    for (int ks = 0; ks < 4; ks++) {
      bf16x8 af[2], bfr[2];
      for (int ti = 0; ti < 2; ti++) af[ti] = *(const bf16x8*)&As[aoff[ks][ti]];
      for (int ni = 0; ni < 2; ni++) bfr[ni] = *(const bf16x8*)&Bs[boff[ks][ni]];
      for (int ti = 0; ti < 2; ti++)
        for (int ni = 0; ni < 2; ni++)
          acc[ti][ni] = __builtin_amdgcn_mfma_f32_32x32x16_bf16(af[ti], bfr[ni], acc[ti][ni], 0, 0, 0);
    }
  }

  // ---- epilogue: bias(/gelu), bounce through LDS (C layout: col=l&31, row=(reg&3)+8*(reg>>2)+4*lh)
  __syncthreads();
  for (int ti = 0; ti < 2; ti++)
    for (int ni = 0; ni < 2; ni++) {
      int coll = wn * 64 + ni * 32 + l31;
      float bb = bias[rowB0 + coll];
      for (int reg = 0; reg < 16; reg++) {
        int row = wm * 64 + ti * 32 + (reg & 3) + 8 * (reg >> 2) + 4 * lh;
        float v = acc[ti][ni][reg] + bb;
        if constexpr (MODE == 2) v = gelu_fast(v);
        smem[row * 136 + coll] = (bf16)v;
      }
    }
  __syncthreads();
  bf16* ob = out + (size_t)z * 4096 * M;
  for (int p = 0; p < 8; p++) {
    int r = p * 16 + (tid >> 4), c0 = (tid & 15) * 8;
    bf16x8 vv = *(const bf16x8*)&smem[r * 136 + c0];
    if constexpr (MODE == 1) {
      const float* rx = (const float*)resid + (size_t)(rowA0 + r) * 512 + rowB0 + c0;
      for (int j = 0; j < 8; j++) vv[j] = (bf16)((float)vv[j] + rx[j]);
    } else if constexpr (MODE == 3) {
      const bf16* rx = (const bf16*)resid + (size_t)z * residStrideZ + (size_t)(rowA0 + r) * 512 + rowB0 + c0;
      bf16x8 rv = *(const bf16x8*)rx;
      for (int j = 0; j < 8; j++) vv[j] = (bf16)((float)vv[j] + (float)rv[j]);
    }
    *(bf16x8*)&ob[(size_t)(rowA0 + r) * M + rowB0 + c0] = vv;
  }
}

// ---------------- fused attention: dbuf K/V pipeline, fixed-max softmax -------------------
__global__ __launch_bounds__(256, 2) void attn_kernel(const bf16* qkv, bf16* o) {
  const int qt = blockIdx.x >> 6, bh = blockIdx.x & 63, z = blockIdx.y;  // same-head blocks share XCD
  const int b = bh >> 3, h = bh & 7;
  const bf16* base = qkv + (size_t)z * 4096 * 1536 + (size_t)b * 512 * 1536;
  __shared__ bf16 smem[30208];
  bf16* Vt = smem + 16384;
  bf16* Q_area = smem + 16384;
  const int tid = threadIdx.x, wave = tid >> 6, l = tid & 63;
  const int m16 = l & 15, q4 = l >> 4;
  bf16* pw = smem + 20992 + wave * 32 * 72;
  f32x4 zero4 = {0.f, 0.f, 0.f, 0.f};

  for (int i = 0; i < 4; i++) {
    int s = i * 256 + tid, r = s >> 3, kb = s & 7;
    async16(base + (size_t)(qt * 128 + r) * 1536 + h * 64 + ((kb ^ (r & 7)) << 3),
            &Q_area[(i * 256 + wave * 64) * 8]);
  }
  for (int i = 0; i < 2; i++) {
    int s = i * 256 + tid, r = s >> 3, kb = s & 7;
    async16(base + (size_t)r * 1536 + 512 + h * 64 + ((kb ^ (r & 7)) << 3),
            &smem[(i * 256 + wave * 64) * 8]);               // Ks buf0 = [0,4096)
    async16(base + (size_t)r * 1536 + 1024 + h * 64 + (kb << 3),
            &smem[8192 + (i * 256 + wave * 64) * 8]);        // Vs buf0 = [8192,12288)
  }
  f32x4 Oacc[2][4];
  float l_run[2][4];
  for (int rt = 0; rt < 2; rt++)
    for (int cr = 0; cr < 4; cr++) l_run[rt][cr] = 0.f;
  for (int rt = 0; rt < 2; rt++) for (int dt = 0; dt < 4; dt++) Oacc[rt][dt] = zero4;
  __syncthreads();
  bf16x8 qf[2][2];
  for (int rt = 0; rt < 2; rt++)
    for (int ks = 0; ks < 2; ks++) {
      int r = wave * 32 + rt * 16 + m16, kb = ks * 4 + q4;
      bf16x8 q8 = *(const bf16x8*)&Q_area[r * 64 + ((kb ^ (r & 7)) << 3)];
      for (int j = 0; j < 8; j++) q8[j] = (bf16)((float)q8[j] * 0.125f);
      qf[rt][ks] = q8;
    }
  __syncthreads();

  for (int kt = 0; kt < 8; kt++) {
    const int cur = kt & 1, nxt = cur ^ 1;
    bf16* Ks = smem + cur * 4096;
    bf16* Vs = smem + 8192 + cur * 4096;
    bf16* Ksn = smem + nxt * 4096;
    bf16* Vsn = smem + 8192 + nxt * 4096;
    if (kt > 0) __syncthreads();
    if (kt < 7) {
      for (int i = 0; i < 2; i++) {
        int s = i * 256 + tid, r = s >> 3, kb = s & 7;
        async16(base + (size_t)((kt + 1) * 64 + r) * 1536 + 512 + h * 64 + ((kb ^ (r & 7)) << 3),
                &Ksn[(i * 256 + wave * 64) * 8]);
        async16(base + (size_t)((kt + 1) * 64 + r) * 1536 + 1024 + h * 64 + (kb << 3),
                &Vsn[(i * 256 + wave * 64) * 8]);
      }
    }
    {
      int d = tid & 63, kb2 = (tid >> 6) * 16;
      for (int g = 0; g < 2; g++) {
        int kbase = kb2 + g * 8;
        bf16 tmp[8];
        for (int j = 0; j < 8; j++) tmp[j] = Vs[(kbase + j) * 64 + d];
        *(bf16x8*)&Vt[d * 72 + kbase] = *(const bf16x8*)tmp;
      }
    }
    f32x4 S[2][4];
    for (int rt = 0; rt < 2; rt++)
      for (int ct = 0; ct < 4; ct++) {
        f32x4 a = zero4;
        for (int ks = 0; ks < 2; ks++) {
          int n = ct * 16 + m16, kb = (ks * 4 + q4) ^ (n & 7);
          bf16x8 kf = *(const bf16x8*)&Ks[n * 64 + (kb << 3)];
          a = __builtin_amdgcn_mfma_f32_16x16x32_bf16(qf[rt][ks], kf, a, 0, 0, 0);
        }
        S[rt][ct] = a;
      }
    for (int rt = 0; rt < 2; rt++)
      for (int cr = 0; cr < 4; cr++) {
        float rs = 0.f;
        for (int ct = 0; ct < 4; ct++) {
          float p = __expf(S[rt][ct][cr]);
          S[rt][ct][cr] = p; rs += p;
        }
        rs += __shfl_xor(rs, 1); rs += __shfl_xor(rs, 2);
        rs += __shfl_xor(rs, 4); rs += __shfl_xor(rs, 8);
        l_run[rt][cr] += rs;
      }
    for (int rt = 0; rt < 2; rt++)
      for (int ct = 0; ct < 4; ct++)
        for (int cr = 0; cr < 4; cr++)
          pw[(rt * 16 + q4 * 4 + cr) * 72 + ct * 16 + m16] = (bf16)S[rt][ct][cr];
    __syncthreads();
    for (int rt = 0; rt < 2; rt++)
      for (int dt = 0; dt < 4; dt++) {
        f32x4 a = Oacc[rt][dt];
        for (int ks = 0; ks < 2; ks++) {
          bf16x8 pf = *(const bf16x8*)&pw[(rt * 16 + m16) * 72 + ks * 32 + q4 * 8];
          bf16x8 vf = *(const bf16x8*)&Vt[(dt * 16 + m16) * 72 + ks * 32 + q4 * 8];
          a = __builtin_amdgcn_mfma_f32_16x16x32_bf16(pf, vf, a, 0, 0, 0);
        }
        Oacc[rt][dt] = a;
      }
  }
  bf16* ob = o + (size_t)z * 4096 * 512 + (size_t)(b * 512 + qt * 128 + wave * 32) * 512 + h * 64;
  for (int rt = 0; rt < 2; rt++)
    for (int dt = 0; dt < 4; dt++)
      for (int cr = 0; cr < 4; cr++) {
        int r = rt * 16 + q4 * 4 + cr;
        ob[(size_t)r * 512 + dt * 16 + m16] = (bf16)(Oacc[rt][dt][cr] / l_run[rt][cr]);
      }
}

// ---------------- stats: prim_sum fp32, per-expert col sums, uvar partials ----------------
__global__ __launch_bounds__(256) void stats_k(const bf16* eout, const float* x,
                                               float* prim_sum, float* mean_acc, float* accum) {
  const int r0 = blockIdx.x * 32;
  const int tid = threadIdx.x;
  const int c0 = tid * 2;
  float cs[4][2] = {{0.f,0.f},{0.f,0.f},{0.f,0.f},{0.f,0.f}};
  float sd = 0.f, sd2 = 0.f;
  for (int rr = 0; rr < 32; rr++) {
    int row = r0 + rr;
    float s0 = 0.f, s1 = 0.f;
    for (int e = 0; e < 4; e++) {
      const bf16* p = &eout[((size_t)e * 4096 + row) * 512 + c0];
      float f0 = (float)p[0], f1 = (float)p[1];
      cs[e][0] += f0; cs[e][1] += f1;
      s0 += f0; s1 += f1;
    }
    prim_sum[(size_t)row * 512 + c0]     = s0;
    prim_sum[(size_t)row * 512 + c0 + 1] = s1;
    float d0 = x[(size_t)row * 512 + c0]     - s0 * 0.25f;
    float d1 = x[(size_t)row * 512 + c0 + 1] - s1 * 0.25f;
    sd += d0 + d1; sd2 += d0 * d0 + d1 * d1;
  }
  for (int e = 0; e < 4; e++) {
    atomicAdd(&mean_acc[e * 512 + c0],     cs[e][0]);
    atomicAdd(&mean_acc[e * 512 + c0 + 1], cs[e][1]);
  }
  for (int off = 32; off > 0; off >>= 1) { sd += __shfl_down(sd, off); sd2 += __shfl_down(sd2, off); }
  __shared__ float r1[4], r2[4];
  if ((tid & 63) == 0) { r1[tid >> 6] = sd; r2[tid >> 6] = sd2; }
  __syncthreads();
  if (tid == 0) {
    atomicAdd(&accum[0], r1[0] + r1[1] + r1[2] + r1[3]);
    atomicAdd(&accum[1], r2[0] + r2[1] + r2[2] + r2[3]);
  }
}

// ---------------- finalize: ortho * uvar -> rate ------------------------------------------
__global__ void finalize_k(const float* mean_acc, const float* accum, float* rate) {
  const int l = threadIdx.x;
  float me[4][8];
  for (int e = 0; e < 4; e++)
    for (int j = 0; j < 8; j++) me[e][j] = mean_acc[e * 512 + l * 8 + j] * (1.f / 4096.f);
  float dot[4][4];
  for (int e = 0; e < 4; e++)
    for (int f = e; f < 4; f++) {
      float d = 0.f;
      for (int j = 0; j < 8; j++) d += me[e][j] * me[f][j];
      for (int off = 32; off > 0; off >>= 1) d += __shfl_xor(d, off);
      dot[e][f] = d; dot[f][e] = d;
    }
  float nrm[4];
  for (int e = 0; e < 4; e++) nrm[e] = sqrtf(dot[e][e]);
  float acc = 0.f;
  for (int e = 0; e < 4; e++)
    for (int f = 0; f < 4; f++) {
      float g = dot[e][f] / (nrm[e] * nrm[f]) - (e == f ? 1.f : 0.f);
      acc += g * g;
    }
  float ortho = 1.f - acc * (1.f / 16.f);
  float n = 2097152.f;
  float uvar = (accum[1] - accum[0] * accum[0] / n) / (n - 1.f);
  float sat = ortho * uvar;
  if (l == 0) rate[0] = (sat > 0.01f) ? 0.01f : 0.f;
}

// ---------------- combine: out = (prim_sum + rate*ghost)/6 --------------------------------
__global__ __launch_bounds__(256) void combine_k(const float* prim, const bf16* ghost,
                                                 const float* rate, float* out) {
  float r = rate[0];
  int i = blockIdx.x * 256 + threadIdx.x;
  f32x4 p = ((const f32x4*)prim)[i];
  const bf16* g = ghost + (size_t)i * 4;
  f32x4 o;
  for (int j = 0; j < 4; j++) o[j] = (p[j] + r * (float)g[j]) * (1.f / 6.f);
  ((f32x4*)out)[i] = o;
}

extern "C" void kernel_launch(void* const* d_in, const int* in_sizes, int n_in,
                              void* d_out, int out_size, void* d_ws, size_t ws_size,
                              hipStream_t stream) {
  const float* x       = (const float*)d_in[0];
  const float* p_ln1_s = (const float*)d_in[2];
  const float* p_ln1_b = (const float*)d_in[3];
  const float* p_wqkv  = (const float*)d_in[4];
  const float* p_bqkv  = (const float*)d_in[5];
  const float* p_wo    = (const float*)d_in[6];
  const float* p_bo    = (const float*)d_in[7];
  const float* p_ln2_s = (const float*)d_in[8];
  const float* p_ln2_b = (const float*)d_in[9];
  const float* p_w1    = (const float*)d_in[10];
  const float* p_b1    = (const float*)d_in[11];
  const float* p_w2    = (const float*)d_in[12];
  const float* p_b2    = (const float*)d_in[13];
  const float* g_ln1_s = (const float*)d_in[14];
  const float* g_ln1_b = (const float*)d_in[15];
  const float* g_wqkv  = (const float*)d_in[16];
  const float* g_bqkv  = (const float*)d_in[17];
  const float* g_wo    = (const float*)d_in[18];
  const float* g_bo    = (const float*)d_in[19];
  const float* g_ln2_s = (const float*)d_in[20];
  const float* g_ln2_b = (const float*)d_in[21];
  const float* g_w1    = (const float*)d_in[22];
  const float* g_b1    = (const float*)d_in[23];
  const float* g_w2    = (const float*)d_in[24];
  const float* g_b2    = (const float*)d_in[25];

  char* ws = (char*)d_ws;
  size_t off = 0;
  auto alloc = [&](size_t bytes) { void* p = ws + off; off += (bytes + 255) & ~(size_t)255; return p; };
  bf16* wt_qkv   = (bf16*)alloc(5ull * 1536 * 512 * 2);
  bf16* wt_wo    = (bf16*)alloc(5ull * 512 * 512 * 2);
  bf16* wt_w1    = (bf16*)alloc(5ull * 2048 * 512 * 2);
  bf16* wt_w2    = (bf16*)alloc(5ull * 512 * 2048 * 2);
  bf16* xn       = (bf16*)alloc(4096ull * 512 * 2);       // shared LN1 output
  bf16* act_a    = (bf16*)alloc(5ull * 4096 * 512 * 2);   // attn-out -> h
  bf16* big      = (bf16*)alloc(5ull * 4096 * 2048 * 2);  // qkv (1536 cols) -> ff (2048)
  bf16* x1       = (bf16*)alloc(5ull * 4096 * 512 * 2);
  bf16* eout     = (bf16*)alloc(5ull * 4096 * 512 * 2);   // per-expert block outputs
  float* prim_sum = (float*)alloc(4096ull * 512 * 4);
  float* bias_eff = (float*)alloc(5ull * 1536 * 4);
  float* mean_acc = (float*)alloc(4 * 512 * 4);
  float* accum    = (float*)alloc(256);

  (void)hipMemsetAsync(bias_eff, 0, 5ull * 1536 * 4, stream);
  (void)hipMemsetAsync(mean_acc, 0, 4 * 512 * 4, stream);
  (void)hipMemsetAsync(accum, 0, 16, stream);

  dim3 tb(32, 8);
  transpose_cvt<1><<<dim3(48, 16, 5), tb, 0, stream>>>(p_wqkv, g_wqkv, wt_qkv, 512, 1536,
      p_ln1_s, p_ln1_b, g_ln1_s, g_ln1_b, p_bqkv, g_bqkv, bias_eff);
  transpose_cvt<0><<<dim3(16, 16, 5), tb, 0, stream>>>(p_wo, g_wo, wt_wo, 512, 512,
      nullptr, nullptr, nullptr, nullptr, nullptr, nullptr, nullptr);
  transpose_cvt<0><<<dim3(64, 16, 5), tb, 0, stream>>>(p_w1, g_w1, wt_w1, 512, 2048,
      nullptr, nullptr, nullptr, nullptr, nullptr, nullptr, nullptr);
  transpose_cvt<0><<<dim3(16, 64, 5), tb, 0, stream>>>(p_w2, g_w2, wt_w2, 2048, 512,
      nullptr, nullptr, nullptr, nullptr, nullptr, nullptr, nullptr);

  ln_plain<<<dim3(4096), 256, 0, stream>>>(x, xn);
  gemm_bt<0><<<dim3(12, 32, 5), 256, 0, stream>>>(xn, 0, wt_qkv, bias_eff, bias_eff + 4ull * 1536,
                                                  512, 1536, big, nullptr, 0);
  attn_kernel<<<dim3(256, 5), 256, 0, stream>>>(big, act_a);
  gemm_bt<1><<<dim3(4, 32, 5), 256, 0, stream>>>(act_a, 4096ll * 512, wt_wo, p_bo, g_bo,
                                                 512, 512, x1, x, 0);
  ln2_kernel<<<dim3(4096, 5), 256, 0, stream>>>(x1, p_ln2_s, p_ln2_b, g_ln2_s, g_ln2_b, act_a);
  gemm_bt<2><<<dim3(16, 32, 5), 256, 0, stream>>>(act_a, 4096ll * 512, wt_w1, p_b1, g_b1,
                                                  512, 2048, big, nullptr, 0);
  gemm_bt<3><<<dim3(4, 32, 5), 256, 0, stream>>>(big, 4096ll * 2048, wt_w2, p_b2, g_b2,
                                                 2048, 512, eout, x1, 4096ll * 512);
  stats_k<<<dim3(128), 256, 0, stream>>>(eout, x, prim_sum, mean_acc, accum);
  finalize_k<<<1, 64, 0, stream>>>(mean_acc, accum, accum + 2);
  combine_k<<<dim3(2048), 256, 0, stream>>>(prim_sum, eout + 4ull * 4096 * 512, accum + 2, (float*)d_out);
}